// Round 1
// baseline (157.012 us; speedup 1.0000x reference)
//
#include <hip/hip_runtime.h>
#include <math.h>

#define BATCH 256
#define M 48
#define T 80
#define NF 6
#define EMIT 10
#define MM (M*M)        // 2304
#define NPT (MM/256)    // 9 keys per thread

#define LOG2PI 1.8378770664093453f

__global__ __launch_bounds__(256, 1)
void em_kernel(const float* __restrict__ g_logits,
               const float* __restrict__ g_traj,
               const float* __restrict__ g_cov,
               float* __restrict__ g_out)
{
    const int b = blockIdx.x;
    const int tid = threadIdx.x;
    const int SEL[3] = {29, 49, 79};

    // ---- LDS (~118 KB; 1 block/CU, grid == 256 CUs) ----
    __shared__ __align__(16) float s_traj[M*T*2];   // 30720 B  [m][t][d]
    __shared__ float s_cov[M*T*3];                  // 46080 B  [m][t][{c00,c01,c11}]
    __shared__ float s_R[3*MM];                     // 27648 B; s_R[0..MM) becomes adj in place
    __shared__ float s_logits[M];
    __shared__ float s_probas[M];
    __shared__ float s_tsel[M*6];                   // [m][tt][d]
    __shared__ float s_d1[M*3];                     // [m][tt]
    __shared__ float s_Pm[M*8];                     // [m][n] padded to 8
    __shared__ float s_traj6[NF*T*2];
    __shared__ float s_cov6[NF*T*3];
    __shared__ float s_t6sel[NF*6];
    __shared__ float s_probas6[NF];
    __shared__ float s_prec[NF*3*3];                // [n][tt][{p00,p01,p11}]
    __shared__ float s_ld[NF*3];
    __shared__ float s_score[M];
    __shared__ float s_worked[M];
    __shared__ int   s_idx[NF];
    __shared__ unsigned s_hist[256];
    __shared__ unsigned s_scan[256];
    __shared__ int s_seld;
    __shared__ int s_sele;

    const float* traj_b = g_traj + (size_t)b * (M*T*2);
    const float* cov_b  = g_cov  + (size_t)b * (M*T*4);

    // ================= load =================
    if (tid < M) s_logits[tid] = g_logits[b*M + tid];
    {
        const float4* src = (const float4*)traj_b;
        float4* dst = (float4*)s_traj;
        for (int i = tid; i < (M*T*2)/4; i += 256) dst[i] = src[i];
    }
    {
        const float4* src = (const float4*)cov_b;
        for (int i = tid; i < M*T; i += 256) {
            float4 c = src[i];
            s_cov[i*3+0] = c.x;   // c00
            s_cov[i*3+1] = c.y;   // c01 (== c10 exactly: A A^T + 0.5I)
            s_cov[i*3+2] = c.w;   // c11
        }
    }
    __syncthreads();

    // ================= tsel, d1, softmax =================
    if (tid < M*3) {
        int m = tid / 3, tt = tid - (tid/3)*3;
        float x = s_traj[m*(T*2) + SEL[tt]*2 + 0];
        float y = s_traj[m*(T*2) + SEL[tt]*2 + 1];
        s_tsel[m*6+tt*2+0] = x;
        s_tsel[m*6+tt*2+1] = y;
        s_d1[tid] = x*x + y*y;
    }
    if (tid < M) {
        float mx = -1e30f;
        for (int j = 0; j < M; ++j) mx = fmaxf(mx, s_logits[j]);
        float sum = 0.f;
        for (int j = 0; j < M; ++j) sum += expf(s_logits[j] - mx);
        s_probas[tid] = expf(s_logits[tid] - mx) / sum;
    }
    __syncthreads();

    // ================= pairwise distances R[tt][m][n] =================
    for (int e = tid; e < 3*MM; e += 256) {
        int tt = e / MM;
        int r  = e - tt*MM;
        int m  = r / M, n = r - (r/M)*M;
        float dot = s_tsel[m*6+tt*2]*s_tsel[n*6+tt*2]
                  + s_tsel[m*6+tt*2+1]*s_tsel[n*6+tt*2+1];
        float v = s_d1[m*3+tt] + s_d1[n*3+tt] - 2.0f*dot;
        s_R[e] = sqrtf(fmaxf(v, 0.0f));   // m==n is exactly 0; clamp guards fp dust
    }
    __syncthreads();

    // ================= exact 15th percentile of R[tt=2] =================
    // order stats 345 & 346 of 2304 nonneg floats: radix-select on bit patterns
    unsigned key[NPT];
    #pragma unroll
    for (int c = 0; c < NPT; ++c) key[c] = __float_as_uint(s_R[2*MM + tid + c*256]);

    float vq[2];
    for (int ri = 0; ri < 2; ++ri) {
        int target = 345 + ri;
        unsigned prefix = 0u, pmask = 0u;
        for (int shift = 24; shift >= 0; shift -= 8) {
            s_hist[tid] = 0u;
            __syncthreads();
            #pragma unroll
            for (int c = 0; c < NPT; ++c) {
                if ((key[c] & pmask) == prefix)
                    atomicAdd(&s_hist[(key[c] >> shift) & 255u], 1u);
            }
            __syncthreads();
            // inclusive Hillis-Steele scan of s_hist -> s_scan
            s_scan[tid] = s_hist[tid];
            __syncthreads();
            for (int off = 1; off < 256; off <<= 1) {
                unsigned add = (tid >= off) ? s_scan[tid - off] : 0u;
                __syncthreads();
                s_scan[tid] += add;
                __syncthreads();
            }
            unsigned inc = s_scan[tid];
            unsigned exc = inc - s_hist[tid];
            if ((int)exc <= target && target < (int)inc) {
                s_seld = tid;
                s_sele = (int)exc;
            }
            __syncthreads();
            target -= s_sele;
            prefix |= ((unsigned)s_seld) << shift;
            pmask  |= (255u << shift);
            __syncthreads();
        }
        vq[ri] = __uint_as_float(prefix);
    }
    // jnp.quantile 'linear': idx = q*(n-1) in f32
    const float qi = 0.15f * 2303.0f;
    const float fr = qi - floorf(qi);
    const float thr = vq[0] * (1.0f - fr) + vq[1] * fr;

    // ================= adjacency (in place over R[0]) =================
    for (int e = tid; e < MM; e += 256) {
        float a = (s_R[e] <= thr && s_R[MM+e] <= thr && s_R[2*MM+e] <= thr) ? 1.0f : 0.0f;
        s_R[e] = a;
    }
    if (tid < M) s_worked[tid] = 1.0f;
    __syncthreads();
    #define s_adj s_R

    // ================= greedy selection of 6 modes =================
    for (int k = 0; k < NF; ++k) {
        if (tid < M) {
            float sc = 0.f;
            for (int n = 0; n < M; ++n) sc += s_adj[tid*M + n] * s_probas[n];
            s_score[tid] = sc * s_worked[tid];
        }
        __syncthreads();
        if (tid == 0) {   // first-max semantics == jnp.argmax
            float best = s_score[0]; int bi = 0;
            for (int m2 = 1; m2 < M; ++m2)
                if (s_score[m2] > best) { best = s_score[m2]; bi = m2; }
            s_idx[k] = bi;
            s_seld = bi;
        }
        __syncthreads();
        if (tid < M) s_worked[tid] *= (1.0f - s_adj[s_seld*M + tid]);
        __syncthreads();
    }

    // ================= init EM state =================
    if (tid < NF) {
        float mx = -1e30f;
        for (int j = 0; j < NF; ++j) mx = fmaxf(mx, s_logits[s_idx[j]]);
        float sum = 0.f;
        for (int j = 0; j < NF; ++j) sum += expf(s_logits[s_idx[j]] - mx);
        s_probas6[tid] = expf(s_logits[s_idx[tid]] - mx) / sum;
    }
    for (int i = tid; i < NF*T*2; i += 256) {
        int n = i / (T*2);
        s_traj6[i] = s_traj[s_idx[n]*(T*2) + (i - n*(T*2))];
    }
    for (int i = tid; i < NF*T*3; i += 256) {
        int n = i / (T*3);
        s_cov6[i] = s_cov[s_idx[n]*(T*3) + (i - n*(T*3))];
    }
    __syncthreads();

    // ================= EM iterations =================
    for (int it = 0; it < EMIT; ++it) {
        // (a) precision + logdet at selector times; snapshot traj6 at selectors
        if (tid < NF*3) {
            int n = tid / 3, tt = tid - (tid/3)*3;
            int base = (n*T + SEL[tt]) * 3;
            float c00 = s_cov6[base+0], c01 = s_cov6[base+1], c11 = s_cov6[base+2];
            float det = c00*c11 - c01*c01;
            s_prec[tid*3+0] =  c11 / det;
            s_prec[tid*3+1] = -c01 / det;
            s_prec[tid*3+2] =  c00 / det;
            s_ld[tid] = logf(det);
        }
        if (tid < NF*6) {
            int n = tid / 6, r = tid - (tid/6)*6;
            s_t6sel[tid] = s_traj6[n*(T*2) + SEL[r>>1]*2 + (r&1)];
        }
        __syncthreads();

        // (b) responsibilities: num = (exp(.)+1e-8) * probas6_old
        for (int i = tid; i < NF*M; i += 256) {
            int n = i / M, m = i - (i/M)*M;
            float q = 0.f;
            #pragma unroll
            for (int tt = 0; tt < 3; ++tt) {
                float dx = s_t6sel[n*6+tt*2+0] - s_tsel[m*6+tt*2+0];
                float dy = s_t6sel[n*6+tt*2+1] - s_tsel[m*6+tt*2+1];
                float p00 = s_prec[(n*3+tt)*3+0];
                float p01 = s_prec[(n*3+tt)*3+1];
                float p11 = s_prec[(n*3+tt)*3+2];
                q += p00*dx*dx + 2.0f*p01*dx*dy + p11*dy*dy;
            }
            float lds = s_ld[n*3+0] + s_ld[n*3+1] + s_ld[n*3+2];
            float ex = -3.0f*LOG2PI - 0.5f*lds - 0.5f*q;
            float pMv = expf(ex) + 1e-8f;
            s_Pm[m*8+n] = pMv * s_probas6[n];
        }
        __syncthreads();
        // normalize over n, fold in probas: P[n][m] = probas[m]*num/(sum_n num + 1e-8)
        if (tid < M) {
            float den = 0.f;
            #pragma unroll
            for (int n = 0; n < NF; ++n) den += s_Pm[tid*8+n];
            den += 1e-8f;
            float f = s_probas[tid] / den;
            #pragma unroll
            for (int n = 0; n < NF; ++n) s_Pm[tid*8+n] *= f;
        }
        __syncthreads();
        // (c) probas6_new
        if (tid < NF) {
            float s = 0.f;
            for (int m2 = 0; m2 < M; ++m2) s += s_Pm[m2*8+tid];
            s_probas6[tid] = s;
        }
        __syncthreads();
        // (d,e) fused M-step: traj6 and cov6 in a single m-loop per (n,t)
        // sum_m p*(t6-x)(t6-x)^T == Sxx - S1*t6  (t6 = S1/p6); +0.5I floor keeps it benign
        for (int i = tid; i < NF*T; i += 256) {
            int n = i / T, t = i - (i/T)*T;
            float S1x=0.f, S1y=0.f, Sxx=0.f, Sxy=0.f, Syy=0.f;
            float C00=0.f, C01=0.f, C11=0.f;
            for (int m2 = 0; m2 < M; ++m2) {
                float p = s_Pm[m2*8+n];
                const float* tp = &s_traj[m2*(T*2) + t*2];
                float x = tp[0], y = tp[1];
                const float* cp = &s_cov[(m2*T + t)*3];
                S1x += p*x;   S1y += p*y;
                Sxx += p*x*x; Sxy += p*x*y; Syy += p*y*y;
                C00 += p*cp[0]; C01 += p*cp[1]; C11 += p*cp[2];
            }
            float p6 = s_probas6[n];
            float tx = S1x / p6, ty = S1y / p6;
            s_traj6[(n*T+t)*2+0] = tx;
            s_traj6[(n*T+t)*2+1] = ty;
            s_cov6[(n*T+t)*3+0] = (C00 + (Sxx - S1x*tx)) / p6;
            s_cov6[(n*T+t)*3+1] = (C01 + (Sxy - S1x*ty)) / p6;
            s_cov6[(n*T+t)*3+2] = (C11 + (Syy - S1y*ty)) / p6;
        }
        __syncthreads();
    }

    // ================= write outputs =================
    float* out_p = g_out;
    float* out_t = g_out + BATCH*NF;
    float* out_c = g_out + BATCH*NF + BATCH*NF*T*2;
    if (tid < NF) out_p[b*NF + tid] = s_probas6[tid];
    for (int i = tid; i < NF*T*2; i += 256)
        out_t[(size_t)b*(NF*T*2) + i] = s_traj6[i];
    for (int i = tid; i < NF*T*4; i += 256) {
        int nt = i >> 2, c = i & 3;
        int cc = (c == 0) ? 0 : ((c == 3) ? 2 : 1);   // symmetric: c10 == c01
        out_c[(size_t)b*(NF*T*4) + i] = s_cov6[nt*3 + cc];
    }
}

extern "C" void kernel_launch(void* const* d_in, const int* in_sizes, int n_in,
                              void* d_out, int out_size, void* d_ws, size_t ws_size,
                              hipStream_t stream) {
    const float* logits = (const float*)d_in[0];
    const float* traj   = (const float*)d_in[1];
    const float* cov    = (const float*)d_in[2];
    float* out = (float*)d_out;
    em_kernel<<<dim3(BATCH), dim3(256), 0, stream>>>(logits, traj, cov, out);
}

// Round 2
// 135.718 us; speedup vs baseline: 1.1569x; 1.1569x over previous
//
#include <hip/hip_runtime.h>
#include <math.h>

#define BATCH 256
#define M 48
#define T 80
#define NF 6
#define EMIT 10
#define MM (M*M)        // 2304
#define NPT (MM/256)    // 9 keys per thread

#define LOG2PI 1.8378770664093453f

__global__ __launch_bounds__(256, 1)
void em_kernel(const float* __restrict__ g_logits,
               const float* __restrict__ g_traj,
               const float* __restrict__ g_cov,
               float* __restrict__ g_out)
{
    const int b = blockIdx.x;
    const int tid = threadIdx.x;
    const int lane = tid & 63;
    const int wv = tid >> 6;
    const int SEL[3] = {29, 49, 79};

    // ---- LDS ~101 KB (1 block/CU) ----
    // SoA features, dense in t (conflict-free b64/b32 reads in the M-step)
    __shared__ __align__(16) float s_fxy[M*T*2];    // float2 {x,y}     30720 B
    __shared__ __align__(16) float s_fc01[M*T*2];   // float2 {c00,c01} 30720 B
    __shared__ float s_fc11[M*T];                   // c11              15360 B
    __shared__ float s_R2[MM];                      // R at tt=2; becomes adj in place
    __shared__ float s_logits[M];
    __shared__ float s_probas[M];
    __shared__ float s_tsel[M*6];                   // [m][tt][d]
    __shared__ float s_d1[M*3];
    __shared__ __align__(16) float s_Pm[M*8];       // [m][n] padded to 8
    __shared__ float s_traj6[NF*T*2];               // [n][t][2]
    __shared__ float s_cov6[NF*T*3];                // [n][t][3]
    __shared__ float s_t6sel[NF*6];
    __shared__ float s_probas6[NF];
    __shared__ float s_prec[NF*3*3];
    __shared__ float s_ld[NF*3];
    __shared__ float s_score[M];
    __shared__ float s_worked[M];
    __shared__ int   s_idx[NF];
    __shared__ unsigned s_hist[256];
    __shared__ unsigned s_wsum[4];
    __shared__ int s_seld;
    __shared__ int s_sele;

    const float* traj_b = g_traj + (size_t)b * (M*T*2);
    const float* cov_b  = g_cov  + (size_t)b * (M*T*4);

    // ================= load =================
    if (tid < M) s_logits[tid] = g_logits[b*M + tid];
    {
        const float4* src = (const float4*)traj_b;   // [m][t][2] == fxy layout
        float4* dst = (float4*)s_fxy;
        for (int i = tid; i < (M*T*2)/4; i += 256) dst[i] = src[i];
    }
    {
        const float4* src = (const float4*)cov_b;
        float2* dstc = (float2*)s_fc01;
        for (int i = tid; i < M*T; i += 256) {
            float4 c = src[i];
            dstc[i] = make_float2(c.x, c.y);   // c01 == c10 exactly (A A^T + 0.5I)
            s_fc11[i] = c.w;
        }
    }
    __syncthreads();

    // ================= tsel, d1, softmax =================
    if (tid < M*3) {
        int m = tid / 3, tt = tid - (tid/3)*3;
        float x = s_fxy[(m*T + SEL[tt])*2 + 0];
        float y = s_fxy[(m*T + SEL[tt])*2 + 1];
        s_tsel[m*6+tt*2+0] = x;
        s_tsel[m*6+tt*2+1] = y;
        s_d1[tid] = x*x + y*y;
    }
    if (tid < M) {
        float mx = -1e30f;
        for (int j = 0; j < M; ++j) mx = fmaxf(mx, s_logits[j]);
        float sum = 0.f;
        for (int j = 0; j < M; ++j) sum += expf(s_logits[j] - mx);
        s_probas[tid] = expf(s_logits[tid] - mx) / sum;
    }
    __syncthreads();

    // ================= pairwise distance at tt=2 only =================
    for (int e = tid; e < MM; e += 256) {
        int m = e / M, n = e - (e/M)*M;
        float dot = s_tsel[m*6+4]*s_tsel[n*6+4] + s_tsel[m*6+5]*s_tsel[n*6+5];
        float v = s_d1[m*3+2] + s_d1[n*3+2] - 2.0f*dot;
        s_R2[e] = sqrtf(fmaxf(v, 0.0f));
    }
    __syncthreads();

    // ================= exact order stat 345 via radix-select =================
    unsigned key[NPT];
    #pragma unroll
    for (int c = 0; c < NPT; ++c) key[c] = __float_as_uint(s_R2[tid + c*256]);

    int target = 345;
    unsigned prefix = 0u, pmask = 0u;
    for (int shift = 24; shift >= 0; shift -= 8) {
        s_hist[tid] = 0u;
        __syncthreads();
        #pragma unroll
        for (int c = 0; c < NPT; ++c) {
            if ((key[c] & pmask) == prefix)
                atomicAdd(&s_hist[(key[c] >> shift) & 255u], 1u);
        }
        __syncthreads();
        unsigned h = s_hist[tid];
        unsigned v = h;
        #pragma unroll
        for (int off = 1; off < 64; off <<= 1) {
            unsigned u = __shfl_up(v, off);
            if (lane >= off) v += u;
        }
        if (lane == 63) s_wsum[wv] = v;
        __syncthreads();
        unsigned pre = 0;
        for (int w = 0; w < wv; ++w) pre += s_wsum[w];
        unsigned exc = pre + v - h;
        if ((int)exc <= target && target < (int)(exc + h)) {
            s_seld = tid;
            s_sele = (int)exc;
        }
        __syncthreads();
        target -= s_sele;
        prefix |= ((unsigned)s_seld) << shift;
        pmask  |= (255u << shift);
    }
    const unsigned k1 = prefix;
    const float v1f = __uint_as_float(k1);

    // order stat 346: count(<=v1); if >=347 it's v1 else min of {x > v1}
    {
        unsigned cnt = 0, mng = 0xFFFFFFFFu;
        #pragma unroll
        for (int c = 0; c < NPT; ++c) {
            if (key[c] <= k1) cnt++;
            else mng = (key[c] < mng) ? key[c] : mng;
        }
        #pragma unroll
        for (int off = 32; off > 0; off >>= 1) {
            cnt += __shfl_down(cnt, off);
            unsigned mo = __shfl_down(mng, off);
            mng = (mo < mng) ? mo : mng;
        }
        if (lane == 0) { s_hist[wv] = cnt; s_hist[4+wv] = mng; }
        __syncthreads();
        unsigned ctot = s_hist[0]+s_hist[1]+s_hist[2]+s_hist[3];
        unsigned mtot = s_hist[4];
        if (s_hist[5] < mtot) mtot = s_hist[5];
        if (s_hist[6] < mtot) mtot = s_hist[6];
        if (s_hist[7] < mtot) mtot = s_hist[7];
        unsigned k2 = (ctot >= 347u) ? k1 : mtot;
        const float v2f = __uint_as_float(k2);
        const float qi = 0.15f * 2303.0f;
        const float fr = qi - floorf(qi);
        float thr = v1f * (1.0f - fr) + v2f * fr;

        // ============ adjacency in place over s_R2 (recompute tt=0,1) ============
        for (int e = tid; e < MM; e += 256) {
            int m = e / M, n = e - (e/M)*M;
            bool a = (s_R2[e] <= thr);
            float d0 = s_tsel[m*6+0]*s_tsel[n*6+0] + s_tsel[m*6+1]*s_tsel[n*6+1];
            float r0 = sqrtf(fmaxf(s_d1[m*3+0] + s_d1[n*3+0] - 2.0f*d0, 0.0f));
            float d1v = s_tsel[m*6+2]*s_tsel[n*6+2] + s_tsel[m*6+3]*s_tsel[n*6+3];
            float r1 = sqrtf(fmaxf(s_d1[m*3+1] + s_d1[n*3+1] - 2.0f*d1v, 0.0f));
            a = a && (r0 <= thr) && (r1 <= thr);
            s_R2[e] = a ? 1.0f : 0.0f;
        }
    }
    if (tid < M) s_worked[tid] = 1.0f;
    __syncthreads();
    #define s_adj s_R2

    // ================= greedy selection of 6 modes =================
    for (int k = 0; k < NF; ++k) {
        if (tid < M) {
            float sc = 0.f;
            for (int n = 0; n < M; ++n) sc += s_adj[tid*M + n] * s_probas[n];
            s_score[tid] = sc * s_worked[tid];
        }
        __syncthreads();
        if (tid == 0) {   // first-max semantics == jnp.argmax
            float best = s_score[0]; int bi = 0;
            for (int m2 = 1; m2 < M; ++m2)
                if (s_score[m2] > best) { best = s_score[m2]; bi = m2; }
            s_idx[k] = bi;
            s_seld = bi;
        }
        __syncthreads();
        if (tid < M) s_worked[tid] *= (1.0f - s_adj[s_seld*M + tid]);
        __syncthreads();
    }

    // ================= init EM state =================
    if (tid < NF) {
        float mx = -1e30f;
        for (int j = 0; j < NF; ++j) mx = fmaxf(mx, s_logits[s_idx[j]]);
        float sum = 0.f;
        for (int j = 0; j < NF; ++j) sum += expf(s_logits[s_idx[j]] - mx);
        s_probas6[tid] = expf(s_logits[s_idx[tid]] - mx) / sum;
    }
    for (int i = tid; i < NF*T*2; i += 256) {
        int n = i / (T*2);
        s_traj6[i] = s_fxy[s_idx[n]*(T*2) + (i - n*(T*2))];
    }
    for (int i = tid; i < NF*T; i += 256) {
        int n = i / T, t = i - (i/T)*T;
        int src = s_idx[n]*T + t;
        s_cov6[(n*T+t)*3+0] = s_fc01[src*2+0];
        s_cov6[(n*T+t)*3+1] = s_fc01[src*2+1];
        s_cov6[(n*T+t)*3+2] = s_fc11[src];
    }
    __syncthreads();

    // ================= EM iterations =================
    for (int it = 0; it < EMIT; ++it) {
        // (a) precision + logdet at selector times; snapshot traj6 at selectors
        if (tid < NF*3) {
            int n = tid / 3, tt = tid - (tid/3)*3;
            int base = (n*T + SEL[tt]) * 3;
            float c00 = s_cov6[base+0], c01 = s_cov6[base+1], c11 = s_cov6[base+2];
            float det = c00*c11 - c01*c01;
            s_prec[tid*3+0] =  c11 / det;
            s_prec[tid*3+1] = -c01 / det;
            s_prec[tid*3+2] =  c00 / det;
            s_ld[tid] = logf(det);
        }
        if (tid < NF*6) {
            int n = tid / 6, r = tid - (tid/6)*6;
            s_t6sel[tid] = s_traj6[n*(T*2) + SEL[r>>1]*2 + (r&1)];
        }
        __syncthreads();

        // (b) responsibilities: num = (exp(.)+1e-8) * probas6_old
        for (int i = tid; i < NF*M; i += 256) {
            int n = i / M, m = i - (i/M)*M;
            float q = 0.f;
            #pragma unroll
            for (int tt = 0; tt < 3; ++tt) {
                float dx = s_t6sel[n*6+tt*2+0] - s_tsel[m*6+tt*2+0];
                float dy = s_t6sel[n*6+tt*2+1] - s_tsel[m*6+tt*2+1];
                float p00 = s_prec[(n*3+tt)*3+0];
                float p01 = s_prec[(n*3+tt)*3+1];
                float p11 = s_prec[(n*3+tt)*3+2];
                q += p00*dx*dx + 2.0f*p01*dx*dy + p11*dy*dy;
            }
            float lds = s_ld[n*3+0] + s_ld[n*3+1] + s_ld[n*3+2];
            float ex = -3.0f*LOG2PI - 0.5f*lds - 0.5f*q;
            float pMv = expf(ex) + 1e-8f;
            s_Pm[m*8+n] = pMv * s_probas6[n];
        }
        __syncthreads();
        // normalize over n, fold in probas
        if (tid < M) {
            float den = 0.f;
            #pragma unroll
            for (int n = 0; n < NF; ++n) den += s_Pm[tid*8+n];
            den += 1e-8f;
            float f = s_probas[tid] / den;
            #pragma unroll
            for (int n = 0; n < NF; ++n) s_Pm[tid*8+n] *= f;
        }
        __syncthreads();
        // (c) probas6_new
        if (tid < NF) {
            float s = 0.f;
            for (int m2 = 0; m2 < M; ++m2) s += s_Pm[m2*8+tid];
            s_probas6[tid] = s;
        }
        __syncthreads();
        // (d) fused M-step: 240 threads, each owns (t, n-pair); reads each
        //     feature once for 2 components. sum p*(t-x)(t-x)^T == Sxx - S1*t
        if (tid < 240) {
            int np = tid / 80;
            int t  = tid - np*80;
            int n0 = np*2, n1 = n0 + 1;
            float S1x0=0,S1y0=0,Sxx0=0,Sxy0=0,Syy0=0,C000=0,C010=0,C110=0;
            float S1x1=0,S1y1=0,Sxx1=0,Sxy1=0,Syy1=0,C001=0,C011=0,C111=0;
            const float2* fxy = (const float2*)s_fxy;
            const float2* fc01 = (const float2*)s_fc01;
            const float2* pm2 = (const float2*)s_Pm;
            #pragma unroll 8
            for (int m2 = 0; m2 < M; ++m2) {
                float2 xy  = fxy[m2*T + t];
                float2 c01 = fc01[m2*T + t];
                float  c11 = s_fc11[m2*T + t];
                float2 pp  = pm2[m2*4 + np];
                float xx = xy.x*xy.x, xyv = xy.x*xy.y, yy = xy.y*xy.y;
                S1x0 += pp.x*xy.x;  S1y0 += pp.x*xy.y;
                Sxx0 += pp.x*xx;    Sxy0 += pp.x*xyv;  Syy0 += pp.x*yy;
                C000 += pp.x*c01.x; C010 += pp.x*c01.y; C110 += pp.x*c11;
                S1x1 += pp.y*xy.x;  S1y1 += pp.y*xy.y;
                Sxx1 += pp.y*xx;    Sxy1 += pp.y*xyv;  Syy1 += pp.y*yy;
                C001 += pp.y*c01.x; C011 += pp.y*c01.y; C111 += pp.y*c11;
            }
            float p60 = s_probas6[n0], p61 = s_probas6[n1];
            float tx0 = S1x0/p60, ty0 = S1y0/p60;
            float tx1 = S1x1/p61, ty1 = S1y1/p61;
            s_traj6[(n0*T+t)*2+0] = tx0;  s_traj6[(n0*T+t)*2+1] = ty0;
            s_traj6[(n1*T+t)*2+0] = tx1;  s_traj6[(n1*T+t)*2+1] = ty1;
            s_cov6[(n0*T+t)*3+0] = (C000 + (Sxx0 - S1x0*tx0)) / p60;
            s_cov6[(n0*T+t)*3+1] = (C010 + (Sxy0 - S1x0*ty0)) / p60;
            s_cov6[(n0*T+t)*3+2] = (C110 + (Syy0 - S1y0*ty0)) / p60;
            s_cov6[(n1*T+t)*3+0] = (C001 + (Sxx1 - S1x1*tx1)) / p61;
            s_cov6[(n1*T+t)*3+1] = (C011 + (Sxy1 - S1x1*ty1)) / p61;
            s_cov6[(n1*T+t)*3+2] = (C111 + (Syy1 - S1y1*ty1)) / p61;
        }
        __syncthreads();
    }

    // ================= write outputs =================
    float* out_p = g_out;
    float* out_t = g_out + BATCH*NF;
    float* out_c = g_out + BATCH*NF + BATCH*NF*T*2;
    if (tid < NF) out_p[b*NF + tid] = s_probas6[tid];
    for (int i = tid; i < NF*T*2; i += 256)
        out_t[(size_t)b*(NF*T*2) + i] = s_traj6[i];
    for (int i = tid; i < NF*T*4; i += 256) {
        int nt = i >> 2, c = i & 3;
        int cc = (c == 0) ? 0 : ((c == 3) ? 2 : 1);   // symmetric: c10 == c01
        out_c[(size_t)b*(NF*T*4) + i] = s_cov6[nt*3 + cc];
    }
}

extern "C" void kernel_launch(void* const* d_in, const int* in_sizes, int n_in,
                              void* d_out, int out_size, void* d_ws, size_t ws_size,
                              hipStream_t stream) {
    const float* logits = (const float*)d_in[0];
    const float* traj   = (const float*)d_in[1];
    const float* cov    = (const float*)d_in[2];
    float* out = (float*)d_out;
    em_kernel<<<dim3(BATCH), dim3(256), 0, stream>>>(logits, traj, cov, out);
}

// Round 3
// 122.274 us; speedup vs baseline: 1.2841x; 1.1100x over previous
//
#include <hip/hip_runtime.h>
#include <math.h>

#define BATCH 256
#define M 48
#define T 80
#define NF 6
#define EMIT 10
#define MM (M*M)        // 2304
#define NPT (MM/256)    // 9 keys per thread

#define LOG2PI 1.8378770664093453f

__global__ __launch_bounds__(256, 1)
void em_kernel(const float* __restrict__ g_logits,
               const float* __restrict__ g_traj,
               const float* __restrict__ g_cov,
               float* __restrict__ g_out)
{
    const int b = blockIdx.x;
    const int tid = threadIdx.x;
    const int lane = tid & 63;
    const int wv = tid >> 6;
    const int SEL[3] = {29, 49, 79};

    // ---- LDS ~94 KB (1 block/CU) ----
    __shared__ __align__(16) float s_fxy[M*T*2];    // float2 {x,y}     30720 B
    __shared__ __align__(16) float s_fc01[M*T*2];   // float2 {c00,c01} 30720 B
    __shared__ float s_fc11[M*T];                   // c11              15360 B
    __shared__ float s_R2[MM];                      // R at tt=2; becomes adj in place
    __shared__ float s_logits[M];
    __shared__ float s_probas[M];
    __shared__ float s_tsel[M*6];                   // [m][tt][d]
    __shared__ float s_d1[M*3];
    __shared__ __align__(16) float s_csel[M*3*4];   // [m][tt][{c00,c01,c11,pad}]
    __shared__ __align__(16) float s_Pm[M*8];       // [m][n] padded to 8
    __shared__ float s_t6sel[NF*6];                 // [n][tt][d]
    __shared__ float s_probas6[NF];
    __shared__ float s_prec[NF*3*3];                // [n*3+tt][{p00,p01,p11}]
    __shared__ float s_ld[NF*3];
    __shared__ int   s_idx[NF];
    __shared__ unsigned s_hist[256];
    __shared__ unsigned s_wsum[4];
    __shared__ int s_seld;
    __shared__ int s_sele;

    const float* traj_b = g_traj + (size_t)b * (M*T*2);
    const float* cov_b  = g_cov  + (size_t)b * (M*T*4);

    // ================= load =================
    if (tid < M) s_logits[tid] = g_logits[b*M + tid];
    {
        const float4* src = (const float4*)traj_b;   // [m][t][2] == fxy layout
        float4* dst = (float4*)s_fxy;
        for (int i = tid; i < (M*T*2)/4; i += 256) dst[i] = src[i];
    }
    {
        const float4* src = (const float4*)cov_b;
        float2* dstc = (float2*)s_fc01;
        for (int i = tid; i < M*T; i += 256) {
            float4 c = src[i];
            dstc[i] = make_float2(c.x, c.y);   // c01 == c10 exactly (A A^T + 0.5I)
            s_fc11[i] = c.w;
        }
    }
    __syncthreads();

    // ============ softmax (wave0) | tsel/d1 (waves 1-3) | csel (all) ============
    if (wv == 0) {
        float lg = (lane < M) ? s_logits[lane] : -1e30f;
        float mx = lg;
        #pragma unroll
        for (int off = 32; off; off >>= 1) mx = fmaxf(mx, __shfl_xor(mx, off));
        float e = (lane < M) ? expf(lg - mx) : 0.f;
        float sum = e;
        #pragma unroll
        for (int off = 32; off; off >>= 1) sum += __shfl_xor(sum, off);
        if (lane < M) s_probas[lane] = e / sum;
    }
    if (tid >= 64 && tid < 64 + M*3) {
        int i = tid - 64;
        int m = i / 3, tt = i - (i/3)*3;
        float x = s_fxy[(m*T + SEL[tt])*2 + 0];
        float y = s_fxy[(m*T + SEL[tt])*2 + 1];
        s_tsel[m*6+tt*2+0] = x;
        s_tsel[m*6+tt*2+1] = y;
        s_d1[i] = x*x + y*y;
    }
    if (tid < M*3) {   // csel staging (waves 0-2; independent of tsel)
        int m = tid / 3, tt = tid - (tid/3)*3;
        int src = m*T + SEL[tt];
        s_csel[tid*4+0] = s_fc01[src*2+0];
        s_csel[tid*4+1] = s_fc01[src*2+1];
        s_csel[tid*4+2] = s_fc11[src];
        s_csel[tid*4+3] = 0.f;
    }
    __syncthreads();

    // ================= pairwise distance at tt=2 only =================
    for (int e = tid; e < MM; e += 256) {
        int m = e / M, n = e - (e/M)*M;
        float dot = s_tsel[m*6+4]*s_tsel[n*6+4] + s_tsel[m*6+5]*s_tsel[n*6+5];
        float v = s_d1[m*3+2] + s_d1[n*3+2] - 2.0f*dot;
        s_R2[e] = sqrtf(fmaxf(v, 0.0f));
    }
    __syncthreads();

    // ================= exact order stat 345 via radix-select =================
    unsigned key[NPT];
    #pragma unroll
    for (int c = 0; c < NPT; ++c) key[c] = __float_as_uint(s_R2[tid + c*256]);

    int target = 345;
    unsigned prefix = 0u, pmask = 0u;
    for (int shift = 24; shift >= 0; shift -= 8) {
        s_hist[tid] = 0u;
        __syncthreads();
        #pragma unroll
        for (int c = 0; c < NPT; ++c) {
            if ((key[c] & pmask) == prefix)
                atomicAdd(&s_hist[(key[c] >> shift) & 255u], 1u);
        }
        __syncthreads();
        unsigned h = s_hist[tid];
        unsigned v = h;
        #pragma unroll
        for (int off = 1; off < 64; off <<= 1) {
            unsigned u = __shfl_up(v, off);
            if (lane >= off) v += u;
        }
        if (lane == 63) s_wsum[wv] = v;
        __syncthreads();
        unsigned pre = 0;
        for (int w = 0; w < wv; ++w) pre += s_wsum[w];
        unsigned exc = pre + v - h;
        if ((int)exc <= target && target < (int)(exc + h)) {
            s_seld = tid;
            s_sele = (int)exc;
        }
        __syncthreads();
        target -= s_sele;
        prefix |= ((unsigned)s_seld) << shift;
        pmask  |= (255u << shift);
    }
    const unsigned k1 = prefix;
    const float v1f = __uint_as_float(k1);

    // order stat 346: count(<=v1); if >=347 it's v1 else min of {x > v1}
    {
        unsigned cnt = 0, mng = 0xFFFFFFFFu;
        #pragma unroll
        for (int c = 0; c < NPT; ++c) {
            if (key[c] <= k1) cnt++;
            else mng = (key[c] < mng) ? key[c] : mng;
        }
        #pragma unroll
        for (int off = 32; off > 0; off >>= 1) {
            cnt += __shfl_down(cnt, off);
            unsigned mo = __shfl_down(mng, off);
            mng = (mo < mng) ? mo : mng;
        }
        if (lane == 0) { s_hist[wv] = cnt; s_hist[4+wv] = mng; }
        __syncthreads();
        unsigned ctot = s_hist[0]+s_hist[1]+s_hist[2]+s_hist[3];
        unsigned mtot = s_hist[4];
        if (s_hist[5] < mtot) mtot = s_hist[5];
        if (s_hist[6] < mtot) mtot = s_hist[6];
        if (s_hist[7] < mtot) mtot = s_hist[7];
        unsigned k2 = (ctot >= 347u) ? k1 : mtot;
        const float v2f = __uint_as_float(k2);
        const float qi = 0.15f * 2303.0f;
        const float fr = qi - floorf(qi);
        float thr = v1f * (1.0f - fr) + v2f * fr;

        // ============ adjacency in place over s_R2 (recompute tt=0,1) ============
        for (int e = tid; e < MM; e += 256) {
            int m = e / M, n = e - (e/M)*M;
            bool a = (s_R2[e] <= thr);
            float d0 = s_tsel[m*6+0]*s_tsel[n*6+0] + s_tsel[m*6+1]*s_tsel[n*6+1];
            float r0 = sqrtf(fmaxf(s_d1[m*3+0] + s_d1[n*3+0] - 2.0f*d0, 0.0f));
            float d1v = s_tsel[m*6+2]*s_tsel[n*6+2] + s_tsel[m*6+3]*s_tsel[n*6+3];
            float r1 = sqrtf(fmaxf(s_d1[m*3+1] + s_d1[n*3+1] - 2.0f*d1v, 0.0f));
            a = a && (r0 <= thr) && (r1 <= thr);
            s_R2[e] = a ? 1.0f : 0.0f;
        }
    }
    __syncthreads();
    #define s_adj s_R2

    // ========= greedy selection (wave 0, no barriers) + EM init =========
    if (wv == 0) {
        const int m = (lane < M) ? lane : (M-1);
        // adj is symmetric: cache column m (== row m), conflict-free reads
        float adjcol[M];
        #pragma unroll
        for (int n = 0; n < M; ++n) adjcol[n] = s_adj[n*M + m];
        // base score: (adj @ probas); only changes via `worked` mask afterwards
        float base = 0.f;
        #pragma unroll
        for (int n = 0; n < M; ++n) base += adjcol[n] * s_probas[n];  // broadcast reads
        float worked = 1.f;
        #pragma unroll
        for (int k = 0; k < NF; ++k) {
            float sc = (lane < M) ? base * worked : -1.f;
            int bi = lane;
            #pragma unroll
            for (int off = 32; off; off >>= 1) {
                float so = __shfl_down(sc, off);
                int io = __shfl_down(bi, off);
                if (so > sc || (so == sc && io < bi)) { sc = so; bi = io; }
            }
            int amax = __shfl(bi, 0);   // first-max semantics == jnp.argmax
            if (lane == 0) s_idx[k] = amax;
            float arow = s_adj[amax*M + m];
            worked *= (1.f - arow);
        }
        // initial probas6 = softmax(logits[idx])
        if (lane < NF) {
            float mx = -1e30f;
            for (int j = 0; j < NF; ++j) mx = fmaxf(mx, s_logits[s_idx[j]]);
            float sum = 0.f;
            for (int j = 0; j < NF; ++j) sum += expf(s_logits[s_idx[j]] - mx);
            s_probas6[lane] = expf(s_logits[s_idx[lane]] - mx) / sum;
        }
        // initial t6sel / prec / logdet from the selected modes
        if (lane < NF*3) {
            int n = lane / 3, tt = lane - (lane/3)*3;
            int m0 = s_idx[n];
            s_t6sel[n*6+tt*2+0] = s_tsel[m0*6+tt*2+0];
            s_t6sel[n*6+tt*2+1] = s_tsel[m0*6+tt*2+1];
            float c00 = s_csel[(m0*3+tt)*4+0];
            float c01 = s_csel[(m0*3+tt)*4+1];
            float c11 = s_csel[(m0*3+tt)*4+2];
            float det = c00*c11 - c01*c01;
            s_prec[lane*3+0] =  c11 / det;
            s_prec[lane*3+1] = -c01 / det;
            s_prec[lane*3+2] =  c00 / det;
            s_ld[lane] = logf(det);
        }
    }
    __syncthreads();

    // ================= EM iterations =================
    // Insight: only SELECTOR-time cov6/traj6 feed the next E-step; the full-T
    // M-step is needed only once, after the final E-step (for the output).
    for (int it = 0; it < EMIT; ++it) {
        // ---- phase X (wave 0): E-step -> P rows + probas6 (shfl-reduced) ----
        if (wv == 0) {
            const int m = (lane < M) ? lane : (M-1);
            float tm[6];
            #pragma unroll
            for (int j = 0; j < 6; ++j) tm[j] = s_tsel[m*6+j];
            float num[NF];
            float den = 1e-8f;
            #pragma unroll
            for (int n = 0; n < NF; ++n) {
                float q = 0.f, lds_ = 0.f;
                #pragma unroll
                for (int tt = 0; tt < 3; ++tt) {
                    float dx = s_t6sel[n*6+tt*2+0] - tm[tt*2+0];
                    float dy = s_t6sel[n*6+tt*2+1] - tm[tt*2+1];
                    float p00 = s_prec[(n*3+tt)*3+0];
                    float p01 = s_prec[(n*3+tt)*3+1];
                    float p11 = s_prec[(n*3+tt)*3+2];
                    q += p00*dx*dx + 2.0f*p01*dx*dy + p11*dy*dy;
                    lds_ += s_ld[n*3+tt];
                }
                float ex = -3.0f*LOG2PI - 0.5f*lds_ - 0.5f*q;
                num[n] = (expf(ex) + 1e-8f) * s_probas6[n];
                den += num[n];
            }
            float f = (lane < M) ? (s_probas[m] / den) : 0.f;
            float P[NF];
            #pragma unroll
            for (int n = 0; n < NF; ++n) P[n] = (lane < M) ? num[n]*f : 0.f;
            // probas6_new
            float s[NF];
            #pragma unroll
            for (int n = 0; n < NF; ++n) {
                float v = P[n];
                #pragma unroll
                for (int off = 32; off; off >>= 1) v += __shfl_down(v, off);
                s[n] = v;
            }
            if (lane < M) {
                *(float4*)&s_Pm[m*8]   = make_float4(P[0],P[1],P[2],P[3]);
                *(float2*)&s_Pm[m*8+4] = make_float2(P[4],P[5]);
            }
            if (lane == 0) {
                #pragma unroll
                for (int n = 0; n < NF; ++n) s_probas6[n] = s[n];
            }
        }
        __syncthreads();

        // ---- phase Y (iters 0..8): selector-only M-step -> prec/ld/t6sel ----
        if (it < EMIT-1) {
            if (wv == 0 && lane < NF*3) {
                int n = lane / 3, tt = lane - (lane/3)*3;
                float S1x=0,S1y=0,Sxx=0,Sxy=0,Syy=0,C00=0,C01=0,C11=0;
                for (int m2 = 0; m2 < M; ++m2) {
                    float x = s_tsel[m2*6+tt*2+0];
                    float y = s_tsel[m2*6+tt*2+1];
                    float4 c = *(const float4*)&s_csel[(m2*3+tt)*4];
                    float p = s_Pm[m2*8+n];
                    S1x += p*x; S1y += p*y;
                    Sxx += p*x*x; Sxy += p*x*y; Syy += p*y*y;
                    C00 += p*c.x; C01 += p*c.y; C11 += p*c.z;
                }
                float p6 = s_probas6[n];
                float tx = S1x/p6, ty = S1y/p6;
                float c00 = (C00 + (Sxx - S1x*tx)) / p6;
                float c01 = (C01 + (Sxy - S1x*ty)) / p6;
                float c11 = (C11 + (Syy - S1y*ty)) / p6;
                float det = c00*c11 - c01*c01;
                s_prec[lane*3+0] =  c11 / det;
                s_prec[lane*3+1] = -c01 / det;
                s_prec[lane*3+2] =  c00 / det;
                s_ld[lane] = logf(det);
                s_t6sel[n*6+tt*2+0] = tx;
                s_t6sel[n*6+tt*2+1] = ty;
            }
            __syncthreads();
        }
    }

    // ================= final full-T M-step -> global output =================
    float* out_p = g_out;
    float2* out_t = (float2*)(g_out + BATCH*NF);
    float4* out_c = (float4*)(g_out + BATCH*NF + BATCH*NF*T*2);
    if (tid < 240) {
        int np = tid / 80;
        int t  = tid - np*80;
        int n0 = np*2, n1 = n0 + 1;
        float S1x0=0,S1y0=0,Sxx0=0,Sxy0=0,Syy0=0,C000=0,C010=0,C110=0;
        float S1x1=0,S1y1=0,Sxx1=0,Sxy1=0,Syy1=0,C001=0,C011=0,C111=0;
        const float2* fxy = (const float2*)s_fxy;
        const float2* fc01 = (const float2*)s_fc01;
        const float2* pm2 = (const float2*)s_Pm;
        #pragma unroll 8
        for (int m2 = 0; m2 < M; ++m2) {
            float2 xy  = fxy[m2*T + t];
            float2 c01 = fc01[m2*T + t];
            float  c11 = s_fc11[m2*T + t];
            float2 pp  = pm2[m2*4 + np];
            float xx = xy.x*xy.x, xyv = xy.x*xy.y, yy = xy.y*xy.y;
            S1x0 += pp.x*xy.x;  S1y0 += pp.x*xy.y;
            Sxx0 += pp.x*xx;    Sxy0 += pp.x*xyv;  Syy0 += pp.x*yy;
            C000 += pp.x*c01.x; C010 += pp.x*c01.y; C110 += pp.x*c11;
            S1x1 += pp.y*xy.x;  S1y1 += pp.y*xy.y;
            Sxx1 += pp.y*xx;    Sxy1 += pp.y*xyv;  Syy1 += pp.y*yy;
            C001 += pp.y*c01.x; C011 += pp.y*c01.y; C111 += pp.y*c11;
        }
        float p60 = s_probas6[n0], p61 = s_probas6[n1];
        float tx0 = S1x0/p60, ty0 = S1y0/p60;
        float tx1 = S1x1/p61, ty1 = S1y1/p61;
        float c000 = (C000 + (Sxx0 - S1x0*tx0)) / p60;
        float c010 = (C010 + (Sxy0 - S1x0*ty0)) / p60;
        float c110 = (C110 + (Syy0 - S1y0*ty0)) / p60;
        float c001 = (C001 + (Sxx1 - S1x1*tx1)) / p61;
        float c011 = (C011 + (Sxy1 - S1x1*ty1)) / p61;
        float c111 = (C111 + (Syy1 - S1y1*ty1)) / p61;
        size_t base = (size_t)b*(NF*T);
        out_t[base + n0*T + t] = make_float2(tx0, ty0);
        out_t[base + n1*T + t] = make_float2(tx1, ty1);
        out_c[base + n0*T + t] = make_float4(c000, c010, c010, c110);
        out_c[base + n1*T + t] = make_float4(c001, c011, c011, c111);
    }
    if (tid < NF) out_p[b*NF + tid] = s_probas6[tid];
}

extern "C" void kernel_launch(void* const* d_in, const int* in_sizes, int n_in,
                              void* d_out, int out_size, void* d_ws, size_t ws_size,
                              hipStream_t stream) {
    const float* logits = (const float*)d_in[0];
    const float* traj   = (const float*)d_in[1];
    const float* cov    = (const float*)d_in[2];
    float* out = (float*)d_out;
    em_kernel<<<dim3(BATCH), dim3(256), 0, stream>>>(logits, traj, cov, out);
}